// Round 1
// baseline (3466.343 us; speedup 1.0000x reference)
//
#include <hip/hip_runtime.h>
#include <hip/hip_bf16.h>

#define T_STEPS 100
#define NG 4096
#define NP 512

typedef __bf16 bf16x8 __attribute__((ext_vector_type(8)));
typedef float f32x4 __attribute__((ext_vector_type(4)));

__device__ __forceinline__ f32x4 mfma_bf16(bf16x8 a, bf16x8 b, f32x4 c) {
  return __builtin_amdgcn_mfma_f32_16x16x32_bf16(a, b, c, 0, 0, 0);
}

// ---------------- f32 -> bf16 conversion, 8 elems/thread ----------------
__global__ __launch_bounds__(256) void cvt_bf16_kernel(const float* __restrict__ in,
                                                       __hip_bfloat16* __restrict__ out,
                                                       int n8) {
  int i = blockIdx.x * 256 + threadIdx.x;
  if (i >= n8) return;
  const float4* p = reinterpret_cast<const float4*>(in) + (size_t)i * 2;
  float4 f0 = p[0], f1 = p[1];
  union { __hip_bfloat16 h[8]; uint4 u; } z;
  z.h[0] = __float2bfloat16(f0.x); z.h[1] = __float2bfloat16(f0.y);
  z.h[2] = __float2bfloat16(f0.z); z.h[3] = __float2bfloat16(f0.w);
  z.h[4] = __float2bfloat16(f1.x); z.h[5] = __float2bfloat16(f1.y);
  z.h[6] = __float2bfloat16(f1.z); z.h[7] = __float2bfloat16(f1.w);
  *(reinterpret_cast<uint4*>(out) + i) = z.u;
}

// ---------------- encoder: h0 = p0 @ W_enc^T  -> bf16 -------------------
// grid 256 blocks (16 n each), block 256 thr. p0 chunk staged in LDS (padded).
__global__ __launch_bounds__(256) void encoder_kernel(const float* __restrict__ p0,
                                                      const float* __restrict__ Wenc,
                                                      __hip_bfloat16* __restrict__ h0) {
  __shared__ float sp[64 * 129];
  const int tid = threadIdx.x;
  const int nb = blockIdx.x * 16;
  const int b = tid & 63;
  const int jg = tid >> 6;
  float acc[4] = {0.f, 0.f, 0.f, 0.f};
  for (int kc = 0; kc < NP; kc += 128) {
    __syncthreads();
    #pragma unroll
    for (int i = 0; i < 32; ++i) {
      int e = tid + i * 256;
      int bb = e >> 7, kk = e & 127;
      sp[bb * 129 + kk] = p0[bb * NP + kc + kk];
    }
    __syncthreads();
    for (int kk = 0; kk < 128; ++kk) {
      float pv = sp[b * 129 + kk];
      #pragma unroll
      for (int jj = 0; jj < 4; ++jj)
        acc[jj] += pv * Wenc[(size_t)(nb + jg * 4 + jj) * NP + kc + kk];
    }
  }
  #pragma unroll
  for (int jj = 0; jj < 4; ++jj)
    h0[(size_t)b * NG + nb + jg * 4 + jj] = __float2bfloat16(acc[jj]);
}

// ---------------- RNN step: z = h@Wh^T + v@Win^T - 0.5*vv ---------------
// grid = 256 (n-strips of 16), block = 512 (8 waves): wave = (m-strip 0..3, k-half 0..1).
// k-halves reduced through LDS; epilogue does vv/z_prev update + relu + bf16 store.
__global__ __launch_bounds__(512) void rnn_step_kernel(
    const __hip_bfloat16* __restrict__ h, int h_stride,
    const __hip_bfloat16* __restrict__ Wh,
    const float* __restrict__ v, const float* __restrict__ Win,
    float* __restrict__ vv, float* __restrict__ zp,
    __hip_bfloat16* __restrict__ gs_out, int t) {
  const int lane = threadIdx.x & 63;
  const int w = threadIdx.x >> 6;
  const int ms = w & 3;   // m strip (16 rows of b)
  const int kh = w >> 2;  // k half (2048 each)
  const int n = blockIdx.x * 16 + (lane & 15);
  const int row_a = ms * 16 + (lane & 15);
  const int k0 = kh * (NG / 2) + (lane >> 4) * 8;

  const __hip_bfloat16* pa = h + (size_t)row_a * h_stride + k0;
  const __hip_bfloat16* pb = Wh + (size_t)n * NG + k0;

  f32x4 acc0{}, acc1{}, acc2{}, acc3{};
  for (int c = 0; c < 16; ++c) {  // 16 * 4 * 32 = 2048 k per wave
    const __hip_bfloat16* qa = pa + c * 128;
    const __hip_bfloat16* qb = pb + c * 128;
    bf16x8 A0 = *reinterpret_cast<const bf16x8*>(qa);
    bf16x8 B0 = *reinterpret_cast<const bf16x8*>(qb);
    acc0 = mfma_bf16(A0, B0, acc0);
    bf16x8 A1 = *reinterpret_cast<const bf16x8*>(qa + 32);
    bf16x8 B1 = *reinterpret_cast<const bf16x8*>(qb + 32);
    acc1 = mfma_bf16(A1, B1, acc1);
    bf16x8 A2 = *reinterpret_cast<const bf16x8*>(qa + 64);
    bf16x8 B2 = *reinterpret_cast<const bf16x8*>(qb + 64);
    acc2 = mfma_bf16(A2, B2, acc2);
    bf16x8 A3 = *reinterpret_cast<const bf16x8*>(qa + 96);
    bf16x8 B3 = *reinterpret_cast<const bf16x8*>(qb + 96);
    acc3 = mfma_bf16(A3, B3, acc3);
  }
  acc0 += acc1; acc2 += acc3; acc0 += acc2;

  __shared__ float red[4][64][4];
  if (kh == 1) {
    #pragma unroll
    for (int j = 0; j < 4; ++j) red[ms][lane][j] = acc0[j];
  }
  __syncthreads();
  if (kh == 0) {
    const float wi0 = Win[n * 2], wi1 = Win[n * 2 + 1];
    #pragma unroll
    for (int j = 0; j < 4; ++j) {
      int b = ms * 16 + (lane >> 4) * 4 + j;
      float z = acc0[j] + red[ms][lane][j];
      z += v[(b * T_STEPS + t) * 2] * wi0 + v[(b * T_STEPS + t) * 2 + 1] * wi1;
      size_t idx = (size_t)b * NG + n;
      float vvo = vv[idx];
      z -= 0.5f * vvo;                         // z uses OLD vv
      float vvn = vvo + 0.1f * (zp[idx] - vvo);  // vv update uses z_{t-1}
      vvn = fmaxf(vvn, 0.0f);
      vv[idx] = vvn;
      zp[idx] = z;                              // store pre-relu z
      gs_out[(size_t)b * (T_STEPS * NG) + n] = __float2bfloat16(fmaxf(z, 0.0f));
    }
  }
}

// ---------------- decoder: logits = gs @ W_dec^T ------------------------
// block = 4 waves (m-stacked), wave = 16m x 64n, grid (100, 8).
__global__ __launch_bounds__(256) void decoder_kernel(const __hip_bfloat16* __restrict__ gs,
                                                      const __hip_bfloat16* __restrict__ Wd,
                                                      float* __restrict__ out) {
  const int lane = threadIdx.x & 63;
  const int w = threadIdx.x >> 6;
  const int m0 = blockIdx.x * 64 + w * 16;
  const int n0 = blockIdx.y * 64;
  const int k0 = (lane >> 4) * 8;
  const __hip_bfloat16* pa = gs + (size_t)(m0 + (lane & 15)) * NG + k0;
  const __hip_bfloat16* pb = Wd + (size_t)(n0 + (lane & 15)) * NG + k0;
  f32x4 a0{}, a1{}, a2{}, a3{};
  for (int c = 0; c < NG / 32; ++c) {
    bf16x8 av = *reinterpret_cast<const bf16x8*>(pa + c * 32);
    bf16x8 b0 = *reinterpret_cast<const bf16x8*>(pb + c * 32);
    bf16x8 b1 = *reinterpret_cast<const bf16x8*>(pb + (size_t)16 * NG + c * 32);
    bf16x8 b2 = *reinterpret_cast<const bf16x8*>(pb + (size_t)32 * NG + c * 32);
    bf16x8 b3 = *reinterpret_cast<const bf16x8*>(pb + (size_t)48 * NG + c * 32);
    a0 = mfma_bf16(av, b0, a0);
    a1 = mfma_bf16(av, b1, a1);
    a2 = mfma_bf16(av, b2, a2);
    a3 = mfma_bf16(av, b3, a3);
  }
  const int col = lane & 15, r4 = (lane >> 4) * 4;
  #pragma unroll
  for (int j = 0; j < 4; ++j) {
    float* po = out + (size_t)(m0 + r4 + j) * NP + n0;
    po[col] = a0[j];
    po[col + 16] = a1[j];
    po[col + 32] = a2[j];
    po[col + 48] = a3[j];
  }
}

// ---------------- log_softmax over rows of 512 (in place) ---------------
__global__ __launch_bounds__(256) void logsoftmax_kernel(float* __restrict__ out) {
  float* row = out + (size_t)blockIdx.x * NP;
  const int tid = threadIdx.x;
  const int lane = tid & 63, wid = tid >> 6;
  float x0 = row[tid], x1 = row[tid + 256];
  float m = fmaxf(x0, x1);
  #pragma unroll
  for (int off = 32; off >= 1; off >>= 1) m = fmaxf(m, __shfl_xor(m, off));
  __shared__ float sred[8];
  if (lane == 0) sred[wid] = m;
  __syncthreads();
  m = fmaxf(fmaxf(sred[0], sred[1]), fmaxf(sred[2], sred[3]));
  float e = __expf(x0 - m) + __expf(x1 - m);
  #pragma unroll
  for (int off = 32; off >= 1; off >>= 1) e += __shfl_xor(e, off);
  if (lane == 0) sred[4 + wid] = e;
  __syncthreads();
  float lse = m + __logf(sred[4] + sred[5] + sred[6] + sred[7]);
  row[tid] = x0 - lse;
  row[tid + 256] = x1 - lse;
}

extern "C" void kernel_launch(void* const* d_in, const int* in_sizes, int n_in,
                              void* d_out, int out_size, void* d_ws, size_t ws_size,
                              hipStream_t stream) {
  const float* v    = (const float*)d_in[0];  // [64,100,2]
  const float* p0   = (const float*)d_in[1];  // [64,512]
  const float* Wenc = (const float*)d_in[2];  // [4096,512]
  const float* Win  = (const float*)d_in[3];  // [4096,2]
  const float* Wh   = (const float*)d_in[4];  // [4096,4096]
  const float* Wdec = (const float*)d_in[5];  // [512,4096]
  float* out = (float*)d_out;                 // [64,100,512]

  char* ws = (char*)d_ws;
  __hip_bfloat16* Wh_bf   = (__hip_bfloat16*)(ws);              // 33,554,432 B
  __hip_bfloat16* Wdec_bf = (__hip_bfloat16*)(ws + 33554432);   //  4,194,304 B
  __hip_bfloat16* h0_bf   = (__hip_bfloat16*)(ws + 37748736);   //    524,288 B
  __hip_bfloat16* gs      = (__hip_bfloat16*)(ws + 38273024);   // 52,428,800 B
  float* vv               = (float*)(ws + 90701824);            //  1,048,576 B
  float* zp               = (float*)(ws + 91750400);            //  1,048,576 B
  // total 92,798,976 B

  hipMemsetAsync(vv, 0, 2 * 1048576, stream);  // vv + zp (contiguous)
  cvt_bf16_kernel<<<8192, 256, 0, stream>>>(Wh, Wh_bf, 2097152);
  cvt_bf16_kernel<<<1024, 256, 0, stream>>>(Wdec, Wdec_bf, 262144);
  encoder_kernel<<<256, 256, 0, stream>>>(p0, Wenc, h0_bf);

  for (int t = 0; t < T_STEPS; ++t) {
    const __hip_bfloat16* h = (t == 0) ? h0_bf : (gs + (size_t)(t - 1) * NG);
    int hs = (t == 0) ? NG : T_STEPS * NG;
    rnn_step_kernel<<<256, 512, 0, stream>>>(h, hs, Wh_bf, v, Win, vv, zp,
                                             gs + (size_t)t * NG, t);
  }

  decoder_kernel<<<dim3(100, 8), 256, 0, stream>>>(gs, Wdec_bf, out);
  logsoftmax_kernel<<<6400, 256, 0, stream>>>(out);
}